// Round 14
// baseline (604.763 us; speedup 1.0000x reference)
//
#include <hip/hip_runtime.h>

#define IN_DIM 23
#define HID 128
#define OUTD 64
#define NGR 64
#define FB_DIM 32      // feat padded to 32 bf16 = 64B aligned rows
#define PH_STRIDE 136  // k_node LDS stride
#define WSCALE 8388608.0f   // 2^23 fixed-point scale for W
#define GEMM_BLKS 256
#define FS_CHUNK 2048       // edges per ticket chunk
#define HWREG_XCC_ID 6164   // hwreg(id=20, offset=0, size=4)

typedef __attribute__((ext_vector_type(8))) short bf16x8;
typedef __attribute__((ext_vector_type(4))) float f32x4;

static __device__ __forceinline__ unsigned short f2bf(float x) {
    unsigned u = __float_as_uint(x);
    unsigned r = (u + 0x7FFFu + ((u >> 16) & 1u)) >> 16;   // RNE
    return (unsigned short)r;
}
static __device__ __forceinline__ float bf2f(unsigned short u) {
    return __uint_as_float((unsigned)u << 16);             // exact
}

// ---------------- A: dst in-degree histogram (native int atomics) ------------
__global__ __launch_bounds__(256) void k_hist(
    const int* __restrict__ dst, int* __restrict__ degi, int n_edges)
{
    int e = blockIdx.x * 256 + threadIdx.x;
    if (e < n_edges) atomicAdd(&degi[dst[e]], 1);
}

// ---------------- A2: transcode feat0 -> bf16 padded rows --------------------
__global__ __launch_bounds__(256) void k_featb(
    const float* __restrict__ feat0, unsigned short* __restrict__ featb,
    int n_nodes)
{
    int i = blockIdx.x * 256 + threadIdx.x;
    if (i >= n_nodes * FB_DIM) return;
    int v = i >> 5, d = i & (FB_DIM - 1);
    float x = (d < IN_DIM) ? feat0[(size_t)v * IN_DIM + d] : 0.f;
    featb[i] = f2bf(x);
}

// ---------------- A3: weight transpose+pad to bf16 MFMA B-operand layout -----
__global__ __launch_bounds__(256) void k_wprep(
    const float* __restrict__ W1, const float* __restrict__ W2,
    unsigned short* __restrict__ W1t, unsigned short* __restrict__ W2t)
{
    int i = blockIdx.x * 256 + threadIdx.x;
    if (i < HID * 32) {
        int h = i >> 5, d = i & 31;
        W1t[i] = f2bf((d < IN_DIM) ? W1[d * HID + h] : 0.f);
    } else if (i < HID * 32 + OUTD * HID) {
        int j = i - HID * 32;
        int o = j >> 7, k = j & 127;
        W2t[j] = f2bf(W2[k * OUTD + o]);
    }
}

// ---------------- A4: payload pack (gid<<24)|wint + W self-term (plain store)
__global__ __launch_bounds__(256) void k_pwg(
    const int* __restrict__ degi, const int* __restrict__ gids,
    unsigned* __restrict__ pwg, int* __restrict__ Wint, int n_nodes)
{
    int v = blockIdx.x * 256 + threadIdx.x;
    if (v >= n_nodes) return;
    float w = 1.0f / ((float)degi[v] + 1.0f);
    int wi = (int)rintf(w * WSCALE);        // <= 2^23, fits 24 bits
    int g = gids[v];
    pwg[v] = ((unsigned)g << 24) | (unsigned)wi;
    Wint[(size_t)v * NGR + g] = wi;         // unique cell, buffer pre-zeroed
}

// ---------------- A5: per-graph node counts via binary search (sorted gids) --
__global__ __launch_bounds__(64) void k_gcnt(
    const int* __restrict__ gids, int* __restrict__ gcnt_i, int n_nodes)
{
    int g = threadIdx.x;
    if (g >= NGR) return;
    int lo0 = 0, hi0 = n_nodes;
    while (lo0 < hi0) { int m = (lo0 + hi0) >> 1; if (gids[m] < g) lo0 = m + 1; else hi0 = m; }
    int lo1 = lo0, hi1 = n_nodes;
    while (lo1 < hi1) { int m = (lo1 + hi1) >> 1; if (gids[m] < g + 1) lo1 = m + 1; else hi1 = m; }
    gcnt_i[g] = lo1 - lo0;
}

// ---------------- B1: per-block local exclusive scan + block totals ----------
__global__ __launch_bounds__(256) void k_scan_local(
    const int* __restrict__ degi, int* __restrict__ local,
    int* __restrict__ bsum, int n_nodes)
{
    int base = blockIdx.x * 1024 + threadIdx.x * 4;
    int4 d = {0, 0, 0, 0};
    if (base + 3 < n_nodes) {
        d = *(const int4*)&degi[base];
    } else {
        if (base + 0 < n_nodes) d.x = degi[base + 0];
        if (base + 1 < n_nodes) d.y = degi[base + 1];
        if (base + 2 < n_nodes) d.z = degi[base + 2];
        if (base + 3 < n_nodes) d.w = degi[base + 3];
    }
    int tsum = d.x + d.y + d.z + d.w;
    int lane = threadIdx.x & 63;
    int wave = threadIdx.x >> 6;
    int s = tsum;
#pragma unroll
    for (int off = 1; off < 64; off <<= 1) {
        int v = __shfl_up(s, off);
        if (lane >= off) s += v;
    }
    __shared__ int wtot[4];
    if (lane == 63) wtot[wave] = s;
    __syncthreads();
    int woff = 0;
#pragma unroll
    for (int i = 0; i < 4; ++i) woff += (i < wave) ? wtot[i] : 0;
    int excl = woff + s - tsum;
    int l0 = excl;
    int l1 = l0 + d.x;
    int l2 = l1 + d.y;
    int l3 = l2 + d.z;
    if (base + 3 < n_nodes) {
        *(int4*)&local[base] = make_int4(l0, l1, l2, l3);
    } else {
        if (base + 0 < n_nodes) local[base + 0] = l0;
        if (base + 1 < n_nodes) local[base + 1] = l1;
        if (base + 2 < n_nodes) local[base + 2] = l2;
        if (base + 3 < n_nodes) local[base + 3] = l3;
    }
    if (threadIdx.x == 255) bsum[blockIdx.x] = excl + tsum;
}

// ---------------- B2: scan the (<=1024) block totals -------------------------
__global__ __launch_bounds__(1024) void k_scan_bsum(
    const int* __restrict__ bsum, int* __restrict__ boff,
    int* __restrict__ rowstart, int nb, int n_nodes, int n_edges)
{
    __shared__ int lds[1024];
    int t = threadIdx.x;
    lds[t] = (t < nb) ? bsum[t] : 0;
    __syncthreads();
    for (int off = 1; off < 1024; off <<= 1) {
        int v = (t >= off) ? lds[t - off] : 0;
        __syncthreads();
        lds[t] += v;
        __syncthreads();
    }
    if (t < nb) boff[t] = (t == 0) ? 0 : lds[t - 1];
    if (t == 0) rowstart[n_nodes] = n_edges;
}

// ---------------- B3: apply block offsets -> rowstart, cursor ----------------
__global__ __launch_bounds__(256) void k_scan_apply(
    const int* __restrict__ local, const int* __restrict__ boff,
    int* __restrict__ rowstart, int* __restrict__ cursor, int n_nodes)
{
    int base = blockIdx.x * 1024 + threadIdx.x * 4;
    int off = boff[blockIdx.x];
    if (base + 3 < n_nodes) {
        int4 l = *(const int4*)&local[base];
        int4 r = make_int4(l.x + off, l.y + off, l.z + off, l.w + off);
        *(int4*)&rowstart[base] = r;
        *(int4*)&cursor[base] = r;
    } else {
        for (int i = 0; i < 4; ++i) {
            if (base + i < n_nodes) {
                int r = local[base + i] + off;
                rowstart[base + i] = r;
                cursor[base + i] = r;
            }
        }
    }
}

// ---------------- C: FUSED fill+scatW, XCD-PINNED via XCC_ID + work stealing -
// Per-group chunk tickets; a block drains its own physical XCD's group first
// (cursor slice, eidx slice, Wint slice all L2-local), then steals remaining
// chunks from other groups. Correct under ANY block->XCD mapping; locality is
// best-effort. One edge-list read per group serves BOTH the dst-CSR fill and
// the src-grouped W scatter.
__global__ __launch_bounds__(256) void k_fillscat(
    const int* __restrict__ src, const int* __restrict__ dst,
    const unsigned* __restrict__ pwg, int* __restrict__ cursor,
    int* __restrict__ eidx, int* __restrict__ Wint, int* __restrict__ tk,
    int n_edges, int n_nodes)
{
    __shared__ int sChunk;
    unsigned xcd = __builtin_amdgcn_s_getreg(HWREG_XCC_ID) & 7u;
    int nchunk = (n_edges + FS_CHUNK - 1) / FS_CHUNK;
#pragma unroll 1
    for (int off = 0; off < 8; ++off) {
        int g = (int)((xcd + off) & 7u);
        int lo = (int)((long long)g * n_nodes / 8);
        int hi = (int)((long long)(g + 1) * n_nodes / 8);
#pragma unroll 1
        for (;;) {
            if (threadIdx.x == 0) sChunk = atomicAdd(&tk[g], 1);
            __syncthreads();
            int c = sChunk;
            __syncthreads();
            if (c >= nchunk) break;
            int e0 = c * FS_CHUNK;
            int e1 = min(e0 + FS_CHUNK, n_edges);
#pragma unroll 1
            for (int e = e0 + threadIdx.x; e < e1; e += 256) {
                int s = src[e];
                int v = dst[e];
                if (v >= lo && v < hi) {
                    int pos = atomicAdd(&cursor[v], 1);
                    eidx[pos] = s;
                }
                if (s >= lo && s < hi) {
                    unsigned p = pwg[v];
                    atomicAdd(&Wint[(size_t)s * NGR + (p >> 24)], (int)(p & 0xFFFFFFu));
                }
            }
        }
    }
}

// ---------------- D: layer-1 gather, QUAD-PER-NODE ---------------------------
__global__ __launch_bounds__(256) void k_agg1(
    const int* __restrict__ rowstart, const int* __restrict__ eidx,
    const unsigned* __restrict__ fbd, const float* __restrict__ feat0,
    unsigned* __restrict__ hnbd, int n_nodes)
{
    int lane = threadIdx.x & 63;
    int quad = lane >> 4, l15 = lane & 15;
    int wglob = (int)((blockIdx.x * 256u + threadIdx.x) >> 6);
    int v = wglob * 4 + quad;
    if (v >= n_nodes) return;
    int e0 = rowstart[v], e1 = rowstart[v + 1];
    int nedge = e1 - e0;
    float a0 = 0.f, a1 = 0.f;
    for (int base = 0; base < nedge; base += 16) {
        int cnt = min(16, nedge - base);
        int idx = 0;
        if (l15 < cnt) idx = eidx[e0 + base + l15];
        unsigned uu[16];
#pragma unroll
        for (int j = 0; j < 16; ++j) {
            int s = __shfl(idx, quad * 16 + min(j, cnt - 1));
            uu[j] = 0u;
            if (j < cnt) uu[j] = fbd[(size_t)s * 16 + l15];
        }
#pragma unroll
        for (int j = 0; j < 16; ++j) {
            a0 += bf2f((unsigned short)(uu[j] & 0xFFFF));
            a1 += bf2f((unsigned short)(uu[j] >> 16));
        }
    }
    int d0 = 2 * l15, d1 = d0 + 1;
    float f0 = (d0 < IN_DIM) ? feat0[(size_t)v * IN_DIM + d0] : 0.f;
    float f1 = (d1 < IN_DIM) ? feat0[(size_t)v * IN_DIM + d1] : 0.f;
    float inv = 1.0f / ((float)nedge + 1.0f);
    unsigned out = (unsigned)f2bf((a0 + f0) * inv)
                 | ((unsigned)f2bf((a1 + f1) * inv) << 16);
    hnbd[(size_t)v * 16 + l15] = out;
}

// ---------------- E: MFMA node transform (unchanged) -------------------------
__global__ __launch_bounds__(256) void k_node(
    const unsigned short* __restrict__ hnb, const unsigned short* __restrict__ W1t,
    const float* __restrict__ b1, const unsigned short* __restrict__ W2t,
    unsigned short* __restrict__ m1, int n_nodes)
{
    __shared__ unsigned short ph[4][16 * PH_STRIDE];
    int wave = threadIdx.x >> 6, lane = threadIdx.x & 63;
    int quad = lane >> 4, l15 = lane & 15;
    const f32x4 z4 = {0.f, 0.f, 0.f, 0.f};

    float bb[8];
#pragma unroll
    for (int t = 0; t < 8; ++t) bb[t] = b1[t * 16 + l15];

    for (int v0 = blockIdx.x * 64 + wave * 16; v0 < n_nodes; v0 += gridDim.x * 64) {
        bf16x8 aH = {0, 0, 0, 0, 0, 0, 0, 0};
        int vA = v0 + l15;
        if (vA < n_nodes) aH = *(const bf16x8*)&hnb[(size_t)vA * FB_DIM + quad * 8];
        f32x4 c1[8];
#pragma unroll
        for (int t = 0; t < 8; ++t) {
            bf16x8 bw = *(const bf16x8*)&W1t[(t * 16 + l15) * 32 + quad * 8];
            c1[t] = __builtin_amdgcn_mfma_f32_16x16x32_bf16(aH, bw, z4, 0, 0, 0);
        }
        float ssq[4] = {0.f, 0.f, 0.f, 0.f};
#pragma unroll
        for (int t = 0; t < 8; ++t) {
#pragma unroll
            for (int r = 0; r < 4; ++r) {
                float x = fmaxf(c1[t][r] + bb[t], 0.f);
                c1[t][r] = x;
                ssq[r] += x * x;
            }
        }
#pragma unroll
        for (int off = 1; off < 16; off <<= 1) {
#pragma unroll
            for (int r = 0; r < 4; ++r) ssq[r] += __shfl_xor(ssq[r], off);
        }
        float inv[4];
#pragma unroll
        for (int r = 0; r < 4; ++r) inv[r] = 1.0f / fmaxf(sqrtf(ssq[r]), 1e-12f);
#pragma unroll
        for (int t = 0; t < 8; ++t)
#pragma unroll
            for (int r = 0; r < 4; ++r)
                ph[wave][(quad * 4 + r) * PH_STRIDE + t * 16 + l15] =
                    f2bf(c1[t][r] * inv[r]);
        f32x4 c2[4] = {z4, z4, z4, z4};
#pragma unroll
        for (int ks = 0; ks < 4; ++ks) {
            bf16x8 aP = *(const bf16x8*)&ph[wave][l15 * PH_STRIDE + ks * 32 + quad * 8];
#pragma unroll
            for (int tn = 0; tn < 4; ++tn) {
                bf16x8 bw = *(const bf16x8*)&W2t[(tn * 16 + l15) * HID + ks * 32 + quad * 8];
                c2[tn] = __builtin_amdgcn_mfma_f32_16x16x32_bf16(aP, bw, c2[tn], 0, 0, 0);
            }
        }
#pragma unroll
        for (int tn = 0; tn < 4; ++tn)
#pragma unroll
            for (int r = 0; r < 4; ++r) {
                int v = v0 + quad * 4 + r;
                if (v < n_nodes) m1[(size_t)v * OUTD + tn * 16 + l15] = f2bf(c2[tn][r]);
            }
    }
}

// ---------------- F: OUT[64x64] = W^T @ M1 via MFMA, K = n_nodes -------------
__global__ __launch_bounds__(256) void k_gemm(
    const int* __restrict__ Wint, const unsigned short* __restrict__ m1,
    float* __restrict__ pb, int n_nodes)
{
    __shared__ unsigned short Wl[32 * 66];
    __shared__ unsigned short Ml[32 * 66];
    int wave = threadIdx.x >> 6, lane = threadIdx.x & 63;
    int quad = lane >> 4, l15 = lane & 15;
    const f32x4 z4 = {0.f, 0.f, 0.f, 0.f};
    f32x4 acc[4] = {z4, z4, z4, z4};
    const float inv_scale = 1.0f / WSCALE;

    int nsteps = (n_nodes + 31) >> 5;
    for (int s = blockIdx.x; s < nsteps; s += gridDim.x) {
        int u0 = s * 32;
        __syncthreads();   // protect LDS from previous step's readers
        for (int i = threadIdx.x; i < 2048; i += 256) {
            int r = i >> 6, c = i & 63;
            int u = u0 + r;
            float wv = 0.f;
            unsigned short mv = 0;
            if (u < n_nodes) {
                wv = (float)Wint[(size_t)u * NGR + c] * inv_scale;
                mv = m1[(size_t)u * OUTD + c];
            }
            Wl[r * 66 + c] = f2bf(wv);
            Ml[r * 66 + c] = mv;
        }
        __syncthreads();
        bf16x8 aF, bF;
#pragma unroll
        for (int j = 0; j < 8; ++j)
            aF[j] = (short)Wl[(quad * 8 + j) * 66 + wave * 16 + l15];
#pragma unroll
        for (int tn = 0; tn < 4; ++tn) {
#pragma unroll
            for (int j = 0; j < 8; ++j)
                bF[j] = (short)Ml[(quad * 8 + j) * 66 + tn * 16 + l15];
            acc[tn] = __builtin_amdgcn_mfma_f32_16x16x32_bf16(aF, bF, acc[tn], 0, 0, 0);
        }
    }
    float* out = pb + (size_t)blockIdx.x * (NGR * OUTD);
#pragma unroll
    for (int tn = 0; tn < 4; ++tn)
#pragma unroll
        for (int r = 0; r < 4; ++r)
            out[(wave * 16 + quad * 4 + r) * OUTD + tn * 16 + l15] = acc[tn][r];
}

// ---------------- G: finalize: reduce partials, mean + b2 --------------------
__global__ __launch_bounds__(256) void k_final(
    const float* __restrict__ pb, const int* __restrict__ gcnt_i,
    const float* __restrict__ b2, float* __restrict__ out)
{
    int i = blockIdx.x * 256 + threadIdx.x;
    if (i >= NGR * OUTD) return;
    float s = 0.f;
    for (int p = 0; p < GEMM_BLKS; ++p) s += pb[(size_t)p * NGR * OUTD + i];
    int g = i >> 6, d = i & 63;
    int c = gcnt_i[g];
    out[i] = (c > 0) ? (s / (float)c + b2[d]) : 0.f;
}

extern "C" void kernel_launch(void* const* d_in, const int* in_sizes, int n_in,
                              void* d_out, int out_size, void* d_ws, size_t ws_size,
                              hipStream_t stream) {
    const float* feat0 = (const float*)d_in[0];
    const float* W1    = (const float*)d_in[1];
    const float* b1    = (const float*)d_in[2];
    const float* W2    = (const float*)d_in[3];
    const float* b2    = (const float*)d_in[4];
    const int*   src   = (const int*)d_in[5];
    const int*   dst   = (const int*)d_in[6];
    const int*   gids  = (const int*)d_in[7];
    int n_edges = in_sizes[5];
    int n_nodes = in_sizes[7];

    int nb = (n_nodes + 1023) / 1024;

    // workspace: bf16 section (16B-aligned) first, then 4B section with the
    // zeroed block (degi | Wint | tk) leading.
    unsigned short* W1t = (unsigned short*)d_ws;
    unsigned short* W2t = W1t + HID * 32;
    unsigned short* hnb = W2t + (size_t)OUTD * HID;
    unsigned short* m1b = hnb + (size_t)n_nodes * FB_DIM;
    unsigned short* featb = m1b + (size_t)n_nodes * OUTD;
    int*   degi     = (int*)(featb + (size_t)n_nodes * FB_DIM);
    int*   Wint     = degi + n_nodes;
    int*   tk       = Wint + (size_t)n_nodes * NGR;
    int*   gcnt_i   = tk + 8;
    int*   rowstart = gcnt_i + NGR;
    int*   cursor   = rowstart + n_nodes + 1;
    int*   local    = cursor + n_nodes;
    int*   bsum     = local + n_nodes;
    int*   boff     = bsum + nb;
    int*   eidx     = boff + nb;
    unsigned* pwg   = (unsigned*)(eidx + n_edges);
    float* pb       = (float*)(pwg + n_nodes);

    size_t zero_units = (size_t)n_nodes * (1 + NGR) + 8;
    hipMemsetAsync(degi, 0, zero_units * 4, stream);

    unsigned blkE = (unsigned)((n_edges + 255) / 256);
    k_hist<<<blkE, 256, 0, stream>>>(dst, degi, n_edges);

    k_featb<<<(unsigned)(((long long)n_nodes * FB_DIM + 255) / 256), 256, 0, stream>>>(
        feat0, featb, n_nodes);
    k_wprep<<<(HID * 32 + OUTD * HID + 255) / 256, 256, 0, stream>>>(W1, W2, W1t, W2t);
    k_pwg<<<(n_nodes + 255) / 256, 256, 0, stream>>>(degi, gids, pwg, Wint, n_nodes);
    k_gcnt<<<1, 64, 0, stream>>>(gids, gcnt_i, n_nodes);

    k_scan_local<<<nb, 256, 0, stream>>>(degi, local, bsum, n_nodes);
    k_scan_bsum<<<1, 1024, 0, stream>>>(bsum, boff, rowstart, nb, n_nodes, n_edges);
    k_scan_apply<<<nb, 256, 0, stream>>>(local, boff, rowstart, cursor, n_nodes);

    k_fillscat<<<2048, 256, 0, stream>>>(src, dst, pwg, cursor, eidx, Wint, tk,
                                         n_edges, n_nodes);

    unsigned blkA = (unsigned)((n_nodes + 15) / 16);
    k_agg1<<<blkA, 256, 0, stream>>>(rowstart, eidx, (const unsigned*)featb, feat0,
                                     (unsigned*)hnb, n_nodes);

    k_node<<<1024, 256, 0, stream>>>(hnb, W1t, b1, W2t, m1b, n_nodes);

    k_gemm<<<GEMM_BLKS, 256, 0, stream>>>(Wint, m1b, pb, n_nodes);

    k_final<<<(NGR * OUTD + 255) / 256, 256, 0, stream>>>(pb, gcnt_i, b2, (float*)d_out);
}